// Round 6
// baseline (157.107 us; speedup 1.0000x reference)
//
#include <hip/hip_runtime.h>
#include <hip/hip_bf16.h>

constexpr int N_NODES = 100000;
constexpr int DIM     = 128;
constexpr int N_EDGES = 640000;

constexpr int SCAN_CHUNK  = 1024;
constexpr int N_CHUNKS    = (N_NODES + SCAN_CHUNK - 1) / SCAN_CHUNK;   // 98
constexpr int WS_STRIDE   = 100352;                                    // ints

constexpr int XCONV_XBLOCKS = N_NODES * DIM / (256 * 8);               // 6250
constexpr int XCONV_WBLOCKS = DIM * DIM / (256 * 8);                   // 8

typedef __attribute__((ext_vector_type(4))) float        f32x4;
typedef __attribute__((ext_vector_type(8))) short        bf16x8;
typedef __attribute__((ext_vector_type(4))) unsigned int u32x4;

static __device__ inline unsigned short f2bf(float f) {
    __hip_bfloat16 h = __float2bfloat16(f);   // RNE
    return *reinterpret_cast<unsigned short*>(&h);
}
static __device__ inline float bf_lo(unsigned u) { return __uint_as_float(u << 16); }
static __device__ inline float bf_hi(unsigned u) { return __uint_as_float(u & 0xffff0000u); }

// ---------------------------------------------------------------------------
// 1) Fused: x->bf16 (blocks < 6250), W->bf16 (blocks >= 6250),
//    zero cnt[0..N] (index N is the scan's ticket counter).
// ---------------------------------------------------------------------------
__global__ __launch_bounds__(256) void gcn_conv(const float* __restrict__ x,
                                                const float* __restrict__ W,
                                                unsigned int* __restrict__ xb,
                                                unsigned int* __restrict__ wb,
                                                int* __restrict__ cnt)
{
    const int b   = blockIdx.x;
    const int gid = b * 256 + threadIdx.x;

    if (gid <= N_NODES) cnt[gid] = 0;   // includes ticket counter at [N_NODES]

    const float*  src;
    unsigned int* dst;
    int i;
    if (b < XCONV_XBLOCKS) {
        src = x;  dst = xb;  i = gid;
    } else {
        src = W;  dst = wb;  i = gid - XCONV_XBLOCKS * 256;
    }
    const f32x4* s4 = reinterpret_cast<const f32x4*>(src);
    f32x4 a = s4[2 * i];
    f32x4 c = s4[2 * i + 1];
    u32x4 o;
    o.x = (unsigned)f2bf(a.x) | ((unsigned)f2bf(a.y) << 16);
    o.y = (unsigned)f2bf(a.z) | ((unsigned)f2bf(a.w) << 16);
    o.z = (unsigned)f2bf(c.x) | ((unsigned)f2bf(c.y) << 16);
    o.w = (unsigned)f2bf(c.z) | ((unsigned)f2bf(c.w) << 16);
    reinterpret_cast<u32x4*>(dst)[i] = o;
}

// ---------------------------------------------------------------------------
// 2) Histogram, 4 edges/thread (int4 load, fire-and-forget atomics)
// ---------------------------------------------------------------------------
__global__ __launch_bounds__(256) void gcn_hist(const int* __restrict__ dst,
                                                int* __restrict__ cnt)
{
    const int e0 = (blockIdx.x * 256 + threadIdx.x) * 4;   // grid exact: 625 blocks
    const int4 d4 = *reinterpret_cast<const int4*>(dst + e0);
    atomicAdd(&cnt[d4.x], 1);
    atomicAdd(&cnt[d4.y], 1);
    atomicAdd(&cnt[d4.z], 1);
    atomicAdd(&cnt[d4.w], 1);
}

// ---------------------------------------------------------------------------
// 3) Single-kernel scan: per-chunk local exclusive prefix -> off;
//    last-arriving block scans the 98 chunk totals -> bpre[] (exclusive).
// ---------------------------------------------------------------------------
__global__ __launch_bounds__(256) void gcn_scan(const int* __restrict__ cnt,
                                                int* __restrict__ off,
                                                int* __restrict__ bsum,
                                                int* __restrict__ bpre,
                                                int* __restrict__ counter)
{
    __shared__ int s[256];
    __shared__ int sticket;
    const int t    = threadIdx.x;
    const int base = blockIdx.x * SCAN_CHUNK + t * 4;

    int v0 = (base + 0 < N_NODES) ? cnt[base + 0] : 0;
    int v1 = (base + 1 < N_NODES) ? cnt[base + 1] : 0;
    int v2 = (base + 2 < N_NODES) ? cnt[base + 2] : 0;
    int v3 = (base + 3 < N_NODES) ? cnt[base + 3] : 0;

    s[t] = v0 + v1 + v2 + v3;
    __syncthreads();
    for (int d = 1; d < 256; d <<= 1) {
        int add = (t >= d) ? s[t - d] : 0;
        __syncthreads();
        s[t] += add;
        __syncthreads();
    }
    int excl = (t > 0) ? s[t - 1] : 0;   // local (within-chunk) exclusive

    if (base + 0 < N_NODES) off[base + 0] = excl;
    if (base + 1 < N_NODES) off[base + 1] = excl + v0;
    if (base + 2 < N_NODES) off[base + 2] = excl + v0 + v1;
    if (base + 3 < N_NODES) off[base + 3] = excl + v0 + v1 + v2;
    if (t == 255) bsum[blockIdx.x] = s[255];

    // last-arriving block scans chunk totals
    __threadfence();
    if (t == 0) sticket = atomicAdd(counter, 1);
    __syncthreads();
    if (sticket == N_CHUNKS - 1) {
        __threadfence();   // acquire: make all bsum writes visible
        int v = (t < N_CHUNKS) ? bsum[t] : 0;
        __syncthreads();   // s[] reuse
        s[t] = v;
        __syncthreads();
        for (int d = 1; d < 256; d <<= 1) {
            int add = (t >= d) ? s[t - d] : 0;
            __syncthreads();
            s[t] += add;
            __syncthreads();
        }
        if (t < N_CHUNKS) bpre[t] = (t > 0) ? s[t - 1] : 0;
    }
}

// ---------------------------------------------------------------------------
// 4) Fill CSR, 4 edges/thread: 4 independent atomics in flight, then stores.
//    off[] is chunk-local; global slot = bpre[d>>10] + atomicAdd(&off[d],1).
//    Post: off[n] = local inclusive prefix.
// ---------------------------------------------------------------------------
__global__ __launch_bounds__(256) void gcn_fill(const int* __restrict__ src,
                                                const int* __restrict__ dst,
                                                int* __restrict__ off,
                                                const int* __restrict__ bpre,
                                                int* __restrict__ csr)
{
    const int e0 = (blockIdx.x * 256 + threadIdx.x) * 4;   // 625 blocks exact
    const int4 d4 = *reinterpret_cast<const int4*>(dst + e0);
    const int4 s4 = *reinterpret_cast<const int4*>(src + e0);

    int p0 = atomicAdd(&off[d4.x], 1);
    int p1 = atomicAdd(&off[d4.y], 1);
    int p2 = atomicAdd(&off[d4.z], 1);
    int p3 = atomicAdd(&off[d4.w], 1);

    csr[p0 + bpre[d4.x >> 10]] = s4.x;
    csr[p1 + bpre[d4.y >> 10]] = s4.y;
    csr[p2 + bpre[d4.z >> 10]] = s4.z;
    csr[p3 + bpre[d4.w >> 10]] = s4.w;
}

// ---------------------------------------------------------------------------
// 5) Gather-aggregate from bf16 x: h[n] = sum(xb[src])/max(deg,1) + xb[n]
//    16 lanes per node, 16B per lane, 4-deep edge unroll for MLP.
// ---------------------------------------------------------------------------
static __device__ inline void acc8(float* acc, u32x4 v) {
    #pragma unroll
    for (int q = 0; q < 4; ++q) {
        unsigned u = v[q];
        acc[2 * q]     += bf_lo(u);
        acc[2 * q + 1] += bf_hi(u);
    }
}

__global__ __launch_bounds__(256) void gcn_gather(
    const unsigned short* __restrict__ xb,
    const int* __restrict__ off,
    const int* __restrict__ bpre,
    const int* __restrict__ csr,
    unsigned int* __restrict__ hb)
{
    const int tid  = threadIdx.x;
    const int lane = tid & 15;                        // 8 dims per lane
    const int n    = blockIdx.x * 16 + (tid >> 4);    // grid exact

    const int pre     = bpre[n >> 10];
    const int end_l   = off[n];
    const int start_l = (n & (SCAN_CHUNK - 1)) ? off[n - 1] : 0;
    const int start   = pre + start_l;
    const int end     = pre + end_l;
    const int col8    = lane * 8;

    float acc[8];
    #pragma unroll
    for (int q = 0; q < 8; ++q) acc[q] = 0.0f;

    int i = start;
    for (; i + 4 <= end; i += 4) {
        int s0 = csr[i], s1 = csr[i + 1], s2 = csr[i + 2], s3 = csr[i + 3];
        u32x4 v0 = *reinterpret_cast<const u32x4*>(xb + (size_t)s0 * DIM + col8);
        u32x4 v1 = *reinterpret_cast<const u32x4*>(xb + (size_t)s1 * DIM + col8);
        u32x4 v2 = *reinterpret_cast<const u32x4*>(xb + (size_t)s2 * DIM + col8);
        u32x4 v3 = *reinterpret_cast<const u32x4*>(xb + (size_t)s3 * DIM + col8);
        acc8(acc, v0); acc8(acc, v1); acc8(acc, v2); acc8(acc, v3);
    }
    for (; i < end; ++i) {
        int s = csr[i];
        u32x4 v = *reinterpret_cast<const u32x4*>(xb + (size_t)s * DIM + col8);
        acc8(acc, v);
    }

    const float inv = 1.0f / fmaxf((float)(end - start), 1.0f);
    const u32x4 xr = *reinterpret_cast<const u32x4*>(xb + (size_t)n * DIM + col8);

    u32x4 o;
    #pragma unroll
    for (int q = 0; q < 4; ++q) {
        float h0 = acc[2 * q]     * inv + bf_lo(xr[q]);
        float h1 = acc[2 * q + 1] * inv + bf_hi(xr[q]);
        o[q] = (unsigned)f2bf(h0) | ((unsigned)f2bf(h1) << 16);
    }
    reinterpret_cast<u32x4*>(hb)[(size_t)n * (DIM / 8) + lane] = o;
}

// ---------------------------------------------------------------------------
// 6) MFMA GEMM: out = relu(h @ W^T + b)   (verified layout, unchanged)
// ---------------------------------------------------------------------------
constexpr int N_TILES = N_NODES / 16;   // 6250

__global__ __launch_bounds__(256) void gcn_mfma(
    const short* __restrict__ hb,
    const short* __restrict__ wb,
    const float* __restrict__ bias,
    float* __restrict__ out)
{
    const int wid  = threadIdx.x >> 6;
    const int lane = threadIdx.x & 63;
    const int tile = blockIdx.x * 4 + wid;
    if (tile >= N_TILES) return;
    const int row0 = tile * 16;

    const int r = lane & 15;
    const int g = lane >> 4;

    bf16x8 wf[8][4];
    #pragma unroll
    for (int c = 0; c < 8; ++c)
        #pragma unroll
        for (int t = 0; t < 4; ++t)
            wf[c][t] = *reinterpret_cast<const bf16x8*>(
                wb + (16 * c + r) * DIM + 32 * t + 8 * g);

    bf16x8 af[4];
    #pragma unroll
    for (int t = 0; t < 4; ++t)
        af[t] = *reinterpret_cast<const bf16x8*>(
            hb + (size_t)(row0 + r) * DIM + 32 * t + 8 * g);

    f32x4 acc[8];
    #pragma unroll
    for (int c = 0; c < 8; ++c) acc[c] = {0.f, 0.f, 0.f, 0.f};

    #pragma unroll
    for (int t = 0; t < 4; ++t)
        #pragma unroll
        for (int c = 0; c < 8; ++c)
            acc[c] = __builtin_amdgcn_mfma_f32_16x16x32_bf16(af[t], wf[c][t], acc[c], 0, 0, 0);

    #pragma unroll
    for (int c = 0; c < 8; ++c) {
        const float bj = bias[16 * c + r];
        #pragma unroll
        for (int q = 0; q < 4; ++q)
            out[(size_t)(row0 + 4 * g + q) * DIM + 16 * c + r] =
                fmaxf(acc[c][q] + bj, 0.0f);
    }
}

// ---------------------------------------------------------------------------
extern "C" void kernel_launch(void* const* d_in, const int* in_sizes, int n_in,
                              void* d_out, int out_size, void* d_ws, size_t ws_size,
                              hipStream_t stream)
{
    const float* x    = (const float*)d_in[0];
    const int*   eidx = (const int*)d_in[1];
    const float* W    = (const float*)d_in[2];
    const float* bias = (const float*)d_in[3];
    float*       out  = (float*)d_out;

    const int* src = eidx;
    const int* dst = eidx + N_EDGES;

    int* cnt     = (int*)d_ws;                      // [N+1] ([N] = ticket)
    int* off     = cnt  + WS_STRIDE;                // [N]
    int* bsum    = off  + WS_STRIDE;                // [128]
    int* bpre    = bsum + 128;                      // [128]
    int* csr     = bpre + 128;                      // [E]
    int* counter = cnt + N_NODES;
    unsigned short* wb = (unsigned short*)(csr + N_EDGES);   // [128*128]
    unsigned short* hb = wb + (size_t)DIM * DIM;             // [N*128] bf16

    // xb lives in d_out's first half; fully overwritten by gcn_mfma each call.
    unsigned short* xb = (unsigned short*)d_out;

    gcn_conv <<<XCONV_XBLOCKS + XCONV_WBLOCKS, 256, 0, stream>>>(
        x, W, (unsigned int*)xb, (unsigned int*)wb, cnt);
    gcn_hist <<<N_EDGES / (256 * 4), 256, 0, stream>>>(dst, cnt);
    gcn_scan <<<N_CHUNKS, 256, 0, stream>>>(cnt, off, bsum, bpre, counter);
    gcn_fill <<<N_EDGES / (256 * 4), 256, 0, stream>>>(src, dst, off, bpre, csr);
    gcn_gather<<<N_NODES / 16, 256, 0, stream>>>(xb, off, bpre, csr, (unsigned int*)hb);
    gcn_mfma <<<(N_TILES + 3) / 4, 256, 0, stream>>>(
        (const short*)hb, (const short*)wb, bias, out);
}

// Round 7
// 108.285 us; speedup vs baseline: 1.4509x; 1.4509x over previous
//
#include <hip/hip_runtime.h>
#include <hip/hip_bf16.h>

constexpr int N_NODES = 100000;
constexpr int DIM     = 128;
constexpr int N_EDGES = 640000;

constexpr int CHUNK     = 1024;                        // nodes per chunk
constexpr int N_CHUNKS  = (N_NODES + CHUNK - 1) / CHUNK;   // 98
constexpr int BINCAP    = 8192;                        // slots per chunk (E[6554]+20 sigma)
constexpr int EPB       = 1024;                        // edges per bin-pass block
constexpr int SRC_BITS  = 17;                          // 100000 < 2^17
constexpr int SRC_MASK  = (1 << SRC_BITS) - 1;

constexpr int XCONV_XBLOCKS = N_NODES * DIM / (256 * 8);               // 6250
constexpr int XCONV_WBLOCKS = DIM * DIM / (256 * 8);                   // 8

typedef __attribute__((ext_vector_type(4))) float        f32x4;
typedef __attribute__((ext_vector_type(8))) short        bf16x8;
typedef __attribute__((ext_vector_type(4))) unsigned int u32x4;

static __device__ inline unsigned short f2bf(float f) {
    __hip_bfloat16 h = __float2bfloat16(f);   // RNE
    return *reinterpret_cast<unsigned short*>(&h);
}
static __device__ inline float bf_lo(unsigned u) { return __uint_as_float(u << 16); }
static __device__ inline float bf_hi(unsigned u) { return __uint_as_float(u & 0xffff0000u); }

// ---------------------------------------------------------------------------
// 1) Fused: x->bf16, W->bf16, zero the 98 bin cursors.
// ---------------------------------------------------------------------------
__global__ __launch_bounds__(256) void gcn_conv(const float* __restrict__ x,
                                                const float* __restrict__ W,
                                                unsigned int* __restrict__ xb,
                                                unsigned int* __restrict__ wb,
                                                int* __restrict__ bincur)
{
    const int b   = blockIdx.x;
    const int gid = b * 256 + threadIdx.x;

    if (b == 0 && threadIdx.x < 128) bincur[threadIdx.x] = 0;

    const float*  src;
    unsigned int* dst;
    int i;
    if (b < XCONV_XBLOCKS) {
        src = x;  dst = xb;  i = gid;
    } else {
        src = W;  dst = wb;  i = gid - XCONV_XBLOCKS * 256;
    }
    const f32x4* s4 = reinterpret_cast<const f32x4*>(src);
    f32x4 a = s4[2 * i];
    f32x4 c = s4[2 * i + 1];
    u32x4 o;
    o.x = (unsigned)f2bf(a.x) | ((unsigned)f2bf(a.y) << 16);
    o.y = (unsigned)f2bf(a.z) | ((unsigned)f2bf(a.w) << 16);
    o.z = (unsigned)f2bf(c.x) | ((unsigned)f2bf(c.y) << 16);
    o.w = (unsigned)f2bf(c.z) | ((unsigned)f2bf(c.w) << 16);
    reinterpret_cast<u32x4*>(dst)[i] = o;
}

// ---------------------------------------------------------------------------
// 2) Bin pass: scatter edges into per-chunk regions (packed src|dstlocal).
//    One global atomic per (block, bin); LDS hist gives in-block rank.
// ---------------------------------------------------------------------------
__global__ __launch_bounds__(256) void gcn_bin(const int* __restrict__ src,
                                               const int* __restrict__ dst,
                                               int* __restrict__ bincur,
                                               unsigned int* __restrict__ bindata)
{
    __shared__ int bh[N_CHUNKS];     // per-bin count (then unused)
    __shared__ int btb[N_CHUNKS];    // per-bin global base for this block

    const int t  = threadIdx.x;
    const int e0 = blockIdx.x * EPB + t * 4;

    if (t < N_CHUNKS) bh[t] = 0;
    __syncthreads();

    const int4 s4 = *reinterpret_cast<const int4*>(src + e0);
    const int4 d4 = *reinterpret_cast<const int4*>(dst + e0);

    int bin[4], pos[4];
    unsigned pv[4];
    const int ds[4] = {d4.x, d4.y, d4.z, d4.w};
    const int ss[4] = {s4.x, s4.y, s4.z, s4.w};
    #pragma unroll
    for (int q = 0; q < 4; ++q) {
        bin[q] = ds[q] >> 10;
        pv[q]  = (unsigned)ss[q] | ((unsigned)(ds[q] & (CHUNK - 1)) << SRC_BITS);
        pos[q] = atomicAdd(&bh[bin[q]], 1);
    }
    __syncthreads();

    if (t < N_CHUNKS) btb[t] = atomicAdd(&bincur[t], bh[t]);
    __syncthreads();

    #pragma unroll
    for (int q = 0; q < 4; ++q)
        bindata[(size_t)bin[q] * BINCAP + btb[bin[q]] + pos[q]] = pv[q];
}

// ---------------------------------------------------------------------------
// 3) Build pass: one block per chunk. Stage bin entries to LDS, per-node
//    hist + scan in LDS, scatter src ids densely IN PLACE over the bin
//    region (fully staged first -> safe). off[n] = start_local | count<<13.
// ---------------------------------------------------------------------------
__global__ __launch_bounds__(256) void gcn_build(const int* __restrict__ bincur,
                                                 unsigned int* __restrict__ bindata,
                                                 int* __restrict__ off)
{
    __shared__ unsigned stage[BINCAP];   // 32 KB
    __shared__ int hist[CHUNK];          // 4 KB: count -> start -> cursor
    __shared__ int s[256];

    const int c  = blockIdx.x;
    const int t  = threadIdx.x;
    const int nb = min(bincur[c], BINCAP);
    unsigned int* region = bindata + (size_t)c * BINCAP;

    for (int e = t; e < nb; e += 256) stage[e] = region[e];
    #pragma unroll
    for (int q = 0; q < 4; ++q) hist[t + 256 * q] = 0;
    __syncthreads();

    for (int e = t; e < nb; e += 256)
        atomicAdd(&hist[stage[e] >> SRC_BITS], 1);
    __syncthreads();

    // scan 1024 counters: thread t owns hist[4t..4t+3]
    int h0 = hist[4 * t + 0], h1 = hist[4 * t + 1];
    int h2 = hist[4 * t + 2], h3 = hist[4 * t + 3];
    s[t] = h0 + h1 + h2 + h3;
    __syncthreads();
    for (int d = 1; d < 256; d <<= 1) {
        int add = (t >= d) ? s[t - d] : 0;
        __syncthreads();
        s[t] += add;
        __syncthreads();
    }
    int excl = (t > 0) ? s[t - 1] : 0;

    const int st0 = excl;
    const int st1 = excl + h0;
    const int st2 = excl + h0 + h1;
    const int st3 = excl + h0 + h1 + h2;
    hist[4 * t + 0] = st0;  hist[4 * t + 1] = st1;
    hist[4 * t + 2] = st2;  hist[4 * t + 3] = st3;

    const int nbase = c * CHUNK;
    if (nbase + 4 * t + 0 < N_NODES) off[nbase + 4 * t + 0] = st0 | (h0 << 13);
    if (nbase + 4 * t + 1 < N_NODES) off[nbase + 4 * t + 1] = st1 | (h1 << 13);
    if (nbase + 4 * t + 2 < N_NODES) off[nbase + 4 * t + 2] = st2 | (h2 << 13);
    if (nbase + 4 * t + 3 < N_NODES) off[nbase + 4 * t + 3] = st3 | (h3 << 13);
    __syncthreads();

    for (int e = t; e < nb; e += 256) {
        unsigned v  = stage[e];
        int slot    = atomicAdd(&hist[v >> SRC_BITS], 1);
        region[slot] = v & SRC_MASK;    // now csr: dense src ids
    }
}

// ---------------------------------------------------------------------------
// 4) Gather-aggregate from bf16 x: h[n] = sum(xb[src])/max(deg,1) + xb[n]
// ---------------------------------------------------------------------------
static __device__ inline void acc8(float* acc, u32x4 v) {
    #pragma unroll
    for (int q = 0; q < 4; ++q) {
        unsigned u = v[q];
        acc[2 * q]     += bf_lo(u);
        acc[2 * q + 1] += bf_hi(u);
    }
}

__global__ __launch_bounds__(256) void gcn_gather(
    const unsigned short* __restrict__ xb,
    const int* __restrict__ off,
    const unsigned int* __restrict__ csr,
    unsigned int* __restrict__ hb)
{
    const int tid  = threadIdx.x;
    const int lane = tid & 15;                        // 8 dims per lane
    const int n    = blockIdx.x * 16 + (tid >> 4);    // grid exact

    const int meta  = off[n];
    const int count = meta >> 13;
    const int start = (n >> 10) * BINCAP + (meta & (BINCAP - 1));
    const int end   = start + count;
    const int col8  = lane * 8;

    float acc[8];
    #pragma unroll
    for (int q = 0; q < 8; ++q) acc[q] = 0.0f;

    int i = start;
    for (; i + 4 <= end; i += 4) {
        int s0 = csr[i], s1 = csr[i + 1], s2 = csr[i + 2], s3 = csr[i + 3];
        u32x4 v0 = *reinterpret_cast<const u32x4*>(xb + (size_t)s0 * DIM + col8);
        u32x4 v1 = *reinterpret_cast<const u32x4*>(xb + (size_t)s1 * DIM + col8);
        u32x4 v2 = *reinterpret_cast<const u32x4*>(xb + (size_t)s2 * DIM + col8);
        u32x4 v3 = *reinterpret_cast<const u32x4*>(xb + (size_t)s3 * DIM + col8);
        acc8(acc, v0); acc8(acc, v1); acc8(acc, v2); acc8(acc, v3);
    }
    for (; i < end; ++i) {
        int s = csr[i];
        u32x4 v = *reinterpret_cast<const u32x4*>(xb + (size_t)s * DIM + col8);
        acc8(acc, v);
    }

    const float inv = 1.0f / fmaxf((float)count, 1.0f);
    const u32x4 xr = *reinterpret_cast<const u32x4*>(xb + (size_t)n * DIM + col8);

    u32x4 o;
    #pragma unroll
    for (int q = 0; q < 4; ++q) {
        float h0 = acc[2 * q]     * inv + bf_lo(xr[q]);
        float h1 = acc[2 * q + 1] * inv + bf_hi(xr[q]);
        o[q] = (unsigned)f2bf(h0) | ((unsigned)f2bf(h1) << 16);
    }
    reinterpret_cast<u32x4*>(hb)[(size_t)n * (DIM / 8) + lane] = o;
}

// ---------------------------------------------------------------------------
// 5) MFMA GEMM: out = relu(h @ W^T + b)   (verified layout, unchanged)
// ---------------------------------------------------------------------------
constexpr int N_TILES = N_NODES / 16;   // 6250

__global__ __launch_bounds__(256) void gcn_mfma(
    const short* __restrict__ hb,
    const short* __restrict__ wb,
    const float* __restrict__ bias,
    float* __restrict__ out)
{
    const int wid  = threadIdx.x >> 6;
    const int lane = threadIdx.x & 63;
    const int tile = blockIdx.x * 4 + wid;
    if (tile >= N_TILES) return;
    const int row0 = tile * 16;

    const int r = lane & 15;
    const int g = lane >> 4;

    bf16x8 wf[8][4];
    #pragma unroll
    for (int c = 0; c < 8; ++c)
        #pragma unroll
        for (int t = 0; t < 4; ++t)
            wf[c][t] = *reinterpret_cast<const bf16x8*>(
                wb + (16 * c + r) * DIM + 32 * t + 8 * g);

    bf16x8 af[4];
    #pragma unroll
    for (int t = 0; t < 4; ++t)
        af[t] = *reinterpret_cast<const bf16x8*>(
            hb + (size_t)(row0 + r) * DIM + 32 * t + 8 * g);

    f32x4 acc[8];
    #pragma unroll
    for (int c = 0; c < 8; ++c) acc[c] = {0.f, 0.f, 0.f, 0.f};

    #pragma unroll
    for (int t = 0; t < 4; ++t)
        #pragma unroll
        for (int c = 0; c < 8; ++c)
            acc[c] = __builtin_amdgcn_mfma_f32_16x16x32_bf16(af[t], wf[c][t], acc[c], 0, 0, 0);

    #pragma unroll
    for (int c = 0; c < 8; ++c) {
        const float bj = bias[16 * c + r];
        #pragma unroll
        for (int q = 0; q < 4; ++q)
            out[(size_t)(row0 + 4 * g + q) * DIM + 16 * c + r] =
                fmaxf(acc[c][q] + bj, 0.0f);
    }
}

// ---------------------------------------------------------------------------
extern "C" void kernel_launch(void* const* d_in, const int* in_sizes, int n_in,
                              void* d_out, int out_size, void* d_ws, size_t ws_size,
                              hipStream_t stream)
{
    const float* x    = (const float*)d_in[0];
    const int*   eidx = (const int*)d_in[1];
    const float* W    = (const float*)d_in[2];
    const float* bias = (const float*)d_in[3];
    float*       out  = (float*)d_out;

    const int* src = eidx;
    const int* dst = eidx + N_EDGES;

    int* bincur = (int*)d_ws;                               // [128]
    int* off    = bincur + 128;                             // [N]
    unsigned int* bindata = (unsigned int*)(off + 100352);  // [98*8192] -> becomes csr
    unsigned short* wb = (unsigned short*)(bindata + (size_t)N_CHUNKS * BINCAP);
    unsigned short* hb = wb + (size_t)DIM * DIM;            // [N*128] bf16

    // xb lives in d_out's first half; fully overwritten by gcn_mfma each call.
    unsigned short* xb = (unsigned short*)d_out;

    gcn_conv <<<XCONV_XBLOCKS + XCONV_WBLOCKS, 256, 0, stream>>>(
        x, W, (unsigned int*)xb, (unsigned int*)wb, bincur);
    gcn_bin  <<<N_EDGES / EPB, 256, 0, stream>>>(src, dst, bincur, bindata);
    gcn_build<<<N_CHUNKS, 256, 0, stream>>>(bincur, bindata, off);
    gcn_gather<<<N_NODES / 16, 256, 0, stream>>>(xb, off, bindata, (unsigned int*)hb);
    gcn_mfma <<<(N_TILES + 3) / 4, 256, 0, stream>>>(
        (const short*)hb, (const short*)wb, bias, out);
}